// Round 1
// baseline (2700.887 us; speedup 1.0000x reference)
//
#include <hip/hip_runtime.h>
#include <hip/hip_bf16.h>

#define NPIX 64
#define NH   6
#define CHD  32
#define DIM  192

typedef unsigned short u16;
typedef unsigned int   u32;

__device__ __forceinline__ float bflo(u32 u) { return __uint_as_float(u << 16); }
__device__ __forceinline__ float bfhi(u32 u) { return __uint_as_float(u & 0xffff0000u); }
__device__ __forceinline__ u16 f2bf(float f) {
    u32 u = __float_as_uint(f);
    u = u + 0x7fffu + ((u >> 16) & 1u);   // RNE
    return (u16)(u >> 16);
}

// One block per window (batch element). 256 threads = 4 waves.
// LDS budget (<=64KB): xs 25088 + lbuf 16896 + q/k/v 13056 + oh 8448 + red 1024 + scl 256 = 64768 B
__global__ __launch_bounds__(256) void wattn_fused(
    const float* __restrict__ x,
    const float* __restrict__ mask,
    const float* __restrict__ qkv_w,
    const float* __restrict__ qkv_b,
    const float* __restrict__ dw_w,
    const float* __restrict__ dw_b,
    const float* __restrict__ proj_w,
    const float* __restrict__ proj_b,
    const float* __restrict__ temp,
    const float* __restrict__ btab,
    float* __restrict__ out,
    int nW)
{
    const int b    = blockIdx.x;
    const int tid  = threadIdx.x;
    const int lane = tid & 63;
    const int wid  = __builtin_amdgcn_readfirstlane(tid >> 6);  // wave id 0..3 (SGPR)

    __shared__ u16   xs[NPIX][196];      // x window, bf16, stride 196 (392B row: 8B-aligned, bank stride 2)
    __shared__ float lbuf[NPIX * 66];    // union: raw qkv [32][66] / logits+attn [64][66]
    __shared__ u16   qh[NPIX][34];       // [pixel][ch] bf16, stride 34 (68B: bank stride 17, odd)
    __shared__ u16   kh[NPIX][34];
    __shared__ u16   vh[NPIX][34];
    __shared__ float oh[NPIX][33];       // attn@v output per head [pixel][ch]
    __shared__ float red[4][NPIX];       // per-wave norm partials
    __shared__ float scl[NPIX];          // per-pixel normalize scale

    // ---- Phase 0: stage x[b] (NHWC, contiguous) into LDS as bf16 ----
    {
        const float* xb = x + (size_t)b * (NPIX * DIM);
        #pragma unroll
        for (int r = 0; r < 12; ++r) {
            int i4 = tid + r * 256;              // 3072 float4 total
            int pp = i4 / 48;
            int c0 = (i4 % 48) * 4;
            float4 v = *(const float4*)(xb + pp * DIM + c0);
            u32 w0 = (u32)f2bf(v.x) | ((u32)f2bf(v.y) << 16);
            u32 w1 = (u32)f2bf(v.z) | ((u32)f2bf(v.w) << 16);
            u32* dst = (u32*)&xs[pp][c0];
            dst[0] = w0; dst[1] = w1;
        }
    }

    const int p  = lane;                 // pixel owned in most phases
    const int py = p >> 3, px = p & 7;
    const float* gmask = mask + (size_t)(b % nW) * (NPIX * NPIX);

    float acc48[48];                     // proj accumulator: out[co = wid+4j][p]
    #pragma unroll
    for (int j = 0; j < 48; ++j) acc48[j] = 0.f;

    for (int h = 0; h < NH; ++h) {
        // ---- build q,k,v (post-dw, normalized) for this head ----
        for (int g = 0; g < 3; ++g) {    // 0=q 1=k 2=v
            const int obase = g * DIM + h * CHD;
            __syncthreads();
            // 1x1 conv GEMM: raw[oc][p], oc = wid + 4*i  (weights: wave-uniform scalar loads)
            {
                float acc[8];
                #pragma unroll
                for (int i = 0; i < 8; ++i) acc[i] = qkv_b[obase + wid + 4 * i];
                #pragma unroll 4
                for (int c0 = 0; c0 < DIM; c0 += 8) {
                    const u32* src = (const u32*)&xs[p][c0];
                    u32 a0 = src[0], a1 = src[1], a2 = src[2], a3 = src[3];
                    float xv[8];
                    xv[0] = bflo(a0); xv[1] = bfhi(a0);
                    xv[2] = bflo(a1); xv[3] = bfhi(a1);
                    xv[4] = bflo(a2); xv[5] = bfhi(a2);
                    xv[6] = bflo(a3); xv[7] = bfhi(a3);
                    #pragma unroll
                    for (int i = 0; i < 8; ++i) {
                        const float* wr = qkv_w + (size_t)(obase + wid + 4 * i) * DIM + c0;
                        #pragma unroll
                        for (int j = 0; j < 8; ++j)
                            acc[i] = fmaf(xv[j], wr[j], acc[i]);
                    }
                }
                #pragma unroll
                for (int i = 0; i < 8; ++i) lbuf[(wid + 4 * i) * 66 + p] = acc[i];
            }
            __syncthreads();
            // depthwise 3x3, SAME pad, local to the 8x8 window
            float dwv[8];
            #pragma unroll
            for (int i = 0; i < 8; ++i) {
                const int o = obase + wid + 4 * i;
                const float* dwr = dw_w + (size_t)o * 9;
                float s = dw_b[o];
                #pragma unroll
                for (int dy = 0; dy < 3; ++dy) {
                    int yy = py + dy - 1;
                    #pragma unroll
                    for (int dx = 0; dx < 3; ++dx) {
                        int xx = px + dx - 1;
                        if (yy >= 0 && yy < 8 && xx >= 0 && xx < 8)
                            s = fmaf(lbuf[(wid + 4 * i) * 66 + yy * 8 + xx], dwr[dy * 3 + dx], s);
                    }
                }
                dwv[i] = s;
            }
            if (g < 2) {
                // L2 norm over the head's 32 channels at each pixel; fold temperature into q
                float ss = 0.f;
                #pragma unroll
                for (int i = 0; i < 8; ++i) ss = fmaf(dwv[i], dwv[i], ss);
                red[wid][p] = ss;
                __syncthreads();
                if (tid < 64) {
                    float tot = red[0][tid] + red[1][tid] + red[2][tid] + red[3][tid];
                    float tf = (g == 0) ? temp[h] : 1.f;
                    scl[tid] = tf / fmaxf(sqrtf(tot), 1e-12f);
                }
                __syncthreads();
                u16(*dst)[34] = (g == 0) ? qh : kh;
                float s = scl[p];
                #pragma unroll
                for (int i = 0; i < 8; ++i) dst[p][wid + 4 * i] = f2bf(dwv[i] * s);
            } else {
                #pragma unroll
                for (int i = 0; i < 8; ++i) vh[p][wid + 4 * i] = f2bf(dwv[i]);
            }
        }
        __syncthreads();
        // ---- logits = q.k + rel_bias + mask ;  m = lane, n = wid + 4*i ----
        {
            u32 krow[16];
            const u32* kr = (const u32*)&kh[p][0];
            #pragma unroll
            for (int t = 0; t < 16; ++t) krow[t] = kr[t];
            #pragma unroll 2
            for (int i = 0; i < 16; ++i) {
                const int n = wid + 4 * i;
                const u32* qr = (const u32*)&qh[n][0];
                float dot = 0.f;
                #pragma unroll
                for (int t = 0; t < 16; ++t) {
                    u32 qv = qr[t], kv = krow[t];
                    dot = fmaf(bflo(qv), bflo(kv), dot);
                    dot = fmaf(bfhi(qv), bfhi(kv), dot);
                }
                const int ny = n >> 3, nx = n & 7;
                const int ridx = (ny - py + 7) * 15 + (nx - px + 7);
                float bias = btab[ridx * NH + h];
                float mval = gmask[n * 64 + p];
                lbuf[n * 66 + p] = dot + bias + mval;
            }
        }
        __syncthreads();
        // ---- softmax over m (row per 64-lane wave) ----
        {
            #pragma unroll 2
            for (int i = 0; i < 16; ++i) {
                const int n = wid * 16 + i;
                float v = lbuf[n * 66 + lane];
                float mx = v;
                #pragma unroll
                for (int off = 32; off >= 1; off >>= 1)
                    mx = fmaxf(mx, __shfl_xor(mx, off, 64));
                float e = __expf(v - mx);
                float s = e;
                #pragma unroll
                for (int off = 32; off >= 1; off >>= 1)
                    s += __shfl_xor(s, off, 64);
                lbuf[n * 66 + lane] = e / s;
            }
        }
        __syncthreads();
        // ---- attn @ v : n = lane, ch = wid + 4*i ----
        {
            float po[8];
            #pragma unroll
            for (int i = 0; i < 8; ++i) po[i] = 0.f;
            for (int m = 0; m < 64; ++m) {
                float a = lbuf[lane * 66 + m];
                #pragma unroll
                for (int i = 0; i < 8; ++i) {
                    float vv = __uint_as_float(((u32)vh[m][wid + 4 * i]) << 16);
                    po[i] = fmaf(a, vv, po[i]);
                }
            }
            #pragma unroll
            for (int i = 0; i < 8; ++i) oh[lane][wid + 4 * i] = po[i];
        }
        __syncthreads();
        // ---- proj partial: acc[co][p] += oh[p][:] . proj_w[co][h*32:] ----
        {
            float ov[32];
            #pragma unroll
            for (int c = 0; c < 32; ++c) ov[c] = oh[lane][c];
            #pragma unroll 4
            for (int j = 0; j < 48; ++j) {
                const float* pw = proj_w + (size_t)(wid + 4 * j) * DIM + h * CHD;
                float s = acc48[j];
                #pragma unroll
                for (int c = 0; c < 32; ++c) s = fmaf(ov[c], pw[c], s);
                acc48[j] = s;
            }
        }
    }
    // ---- epilogue: NCHW store, coalesced over p ----
    {
        float* ob = out + (size_t)b * (DIM * NPIX);
        #pragma unroll 4
        for (int j = 0; j < 48; ++j) {
            const int co = wid + 4 * j;
            ob[co * 64 + lane] = acc48[j] + proj_b[co];
        }
    }
}

extern "C" void kernel_launch(void* const* d_in, const int* in_sizes, int n_in,
                              void* d_out, int out_size, void* d_ws, size_t ws_size,
                              hipStream_t stream)
{
    const float* x      = (const float*)d_in[0];
    const float* mask   = (const float*)d_in[1];
    const float* qkv_w  = (const float*)d_in[2];
    const float* qkv_b  = (const float*)d_in[3];
    const float* dw_w   = (const float*)d_in[4];
    const float* dw_b   = (const float*)d_in[5];
    const float* proj_w = (const float*)d_in[6];
    const float* proj_b = (const float*)d_in[7];
    const float* temp   = (const float*)d_in[8];
    const float* btab   = (const float*)d_in[9];
    float* out = (float*)d_out;

    const int b  = in_sizes[0] / (NPIX * DIM);   // 2048
    const int nW = in_sizes[1] / (NPIX * NPIX);  // 512

    wattn_fused<<<dim3(b), dim3(256), 0, stream>>>(
        x, mask, qkv_w, qkv_b, dw_w, dw_b, proj_w, proj_b, temp, btab, out, nW);
}

// Round 2
// 482.661 us; speedup vs baseline: 5.5958x; 5.5958x over previous
//
#include <hip/hip_runtime.h>

typedef unsigned short u16;
typedef unsigned int   u32;
typedef __attribute__((ext_vector_type(8))) short bf16x8;
typedef __attribute__((ext_vector_type(4))) float f32x4;

#define STR_XS 200   // bf16 elems per xs row   (400 B, 16B-mult, bank 4m -> 2-way free)
#define STR_LB 68    // fp32 elems per lbuf row (272 B, 16B-mult)
#define STR_QK 72    // bf16 elems per qh/kh row (144 B)
#define STR_V  72    // bf16 elems per vh row (ch-major)
#define STR_OH 72    // bf16 elems per oh row

// round-half-up bf16 (differs from RNE only at exact ties: prob 2^-16, 1 ulp)
__device__ __forceinline__ u32 pkbf(float lo, float hi) {
    return __builtin_amdgcn_perm(__float_as_uint(hi) + 0x8000u,
                                 __float_as_uint(lo) + 0x8000u, 0x07060302u);
}
__device__ __forceinline__ u16 sbf(float f) {
    return (u16)((__float_as_uint(f) + 0x8000u) >> 16);
}

__global__ __launch_bounds__(256, 2) void wattn_mfma(
    const float* __restrict__ x, const float* __restrict__ mask,
    const float* __restrict__ qkv_w, const float* __restrict__ qkv_b,
    const float* __restrict__ dw_w, const float* __restrict__ dw_b,
    const float* __restrict__ proj_w, const float* __restrict__ proj_b,
    const float* __restrict__ temp, const float* __restrict__ btab,
    float* __restrict__ out, int nW)
{
    const int b    = blockIdx.x;
    const int tid  = threadIdx.x;
    const int lane = tid & 63;
    const int wid  = __builtin_amdgcn_readfirstlane(tid >> 6);
    const int quad = lane >> 4, l15 = lane & 15;

    __shared__ u16   xs[64 * STR_XS];     // 25600 B  x window bf16 [pix][ch]
    __shared__ float lbuf[64 * STR_LB];   // 17408 B  raw qkv chunk / S / P / out-transpose
    __shared__ u16   qh[64 * STR_QK];     //  9216 B  [pix][ch64] (2 heads)
    __shared__ u16   kh[64 * STR_QK];     //  9216 B
    __shared__ u16   vh[64 * STR_V];      //  9216 B  [ch64][pix]  (B-layout for PV)
    __shared__ u16   oh[64 * STR_OH];     //  9216 B  [pix][ch64]  (A-layout for proj)
    __shared__ float red[4][64];          //  1024 B
    __shared__ float scl[2][64];          //   512 B
    // total 81408 B  -> 2 blocks/CU (2*81408 <= 163840)

    // ---- stage x -> xs (bf16) ----
    {
        const float* xb = x + (size_t)b * 12288;
        #pragma unroll
        for (int r = 0; r < 12; ++r) {
            int i4 = tid + r * 256;
            int pp = i4 / 48, c0 = (i4 % 48) * 4;
            float4 v = *(const float4*)(xb + pp * 192 + c0);
            u32* d = (u32*)&xs[pp * STR_XS + c0];
            d[0] = pkbf(v.x, v.y);
            d[1] = pkbf(v.z, v.w);
        }
    }

    const float* gmask = mask + (size_t)(b % nW) * 4096;
    const int py = lane >> 3, px = lane & 7;

    f32x4 accP[12];   // proj C-frags: [nt 0..2][mt 0..3], cols = wid*48+nt*16+l15
    #pragma unroll
    for (int i = 0; i < 12; ++i) accP[i] = f32x4{0.f, 0.f, 0.f, 0.f};

    for (int it = 0; it < 3; ++it) {
        // ======== build q,k,v for heads 2it, 2it+1 (64-ch chunks) ========
        for (int g = 0; g < 3; ++g) {           // 0=q 1=k 2=v
            const int obase = g * 192 + it * 64;
            __syncthreads();                     // lbuf reuse + (it=0,g=0) xs ready
            // ---- 1x1 GEMM chunk: ch tile = wid ----
            {
                f32x4 C[4];
                #pragma unroll
                for (int mt = 0; mt < 4; ++mt) C[mt] = f32x4{0.f, 0.f, 0.f, 0.f};
                const float* wb = qkv_w + (size_t)(obase + wid * 16 + l15) * 192;
                #pragma unroll
                for (int kf = 0; kf < 6; ++kf) {
                    const float* wp = wb + kf * 32 + quad * 8;
                    float4 b0 = *(const float4*)wp, b1 = *(const float4*)(wp + 4);
                    union { u32 u[4]; bf16x8 v; } fb;
                    fb.u[0] = pkbf(b0.x, b0.y); fb.u[1] = pkbf(b0.z, b0.w);
                    fb.u[2] = pkbf(b1.x, b1.y); fb.u[3] = pkbf(b1.z, b1.w);
                    #pragma unroll
                    for (int mt = 0; mt < 4; ++mt) {
                        bf16x8 a = *(const bf16x8*)&xs[(mt * 16 + l15) * STR_XS + kf * 32 + quad * 8];
                        C[mt] = __builtin_amdgcn_mfma_f32_16x16x32_bf16(a, fb.v, C[mt], 0, 0, 0);
                    }
                }
                float bias = qkv_b[obase + wid * 16 + l15];
                #pragma unroll
                for (int mt = 0; mt < 4; ++mt)
                    #pragma unroll
                    for (int r = 0; r < 4; ++r)
                        lbuf[(mt * 16 + quad * 4 + r) * STR_LB + wid * 16 + l15] = C[mt][r] + bias;
            }
            __syncthreads();
            // ---- depthwise 3x3 (16 ch/thread, pixel = lane) ----
            const int c0 = wid * 16;
            float dwv[16];
            #pragma unroll
            for (int j = 0; j < 16; ++j) dwv[j] = dw_b[obase + c0 + j];
            #pragma unroll
            for (int dy = -1; dy <= 1; ++dy) {
                int yy = py + dy;
                if ((unsigned)yy < 8u) {
                    #pragma unroll
                    for (int dx = -1; dx <= 1; ++dx) {
                        int xx = px + dx;
                        if ((unsigned)xx < 8u) {
                            const float* src = &lbuf[(yy * 8 + xx) * STR_LB + c0];
                            float nb[16];
                            *(f32x4*)&nb[0]  = *(const f32x4*)(src);
                            *(f32x4*)&nb[4]  = *(const f32x4*)(src + 4);
                            *(f32x4*)&nb[8]  = *(const f32x4*)(src + 8);
                            *(f32x4*)&nb[12] = *(const f32x4*)(src + 12);
                            #pragma unroll
                            for (int j = 0; j < 16; ++j)
                                dwv[j] = fmaf(nb[j], dw_w[(obase + c0 + j) * 9 + (dy + 1) * 3 + dx + 1], dwv[j]);
                        }
                    }
                }
            }
            if (g < 2) {
                // L2 norm per (pixel, head); fold temperature into q
                float ss = 0.f;
                #pragma unroll
                for (int j = 0; j < 16; ++j) ss = fmaf(dwv[j], dwv[j], ss);
                red[wid][lane] = ss;
                __syncthreads();
                if (tid < 128) {
                    int p = tid & 63, hh = tid >> 6;
                    float tot = red[2 * hh][p] + red[2 * hh + 1][p];
                    float tf = (g == 0) ? temp[it * 2 + hh] : 1.f;
                    scl[hh][p] = tf / fmaxf(sqrtf(tot), 1e-12f);
                }
                __syncthreads();
                float s = scl[wid >> 1][lane];
                u16* dst = (g == 0) ? qh : kh;
                u32* d = (u32*)&dst[lane * STR_QK + c0];
                #pragma unroll
                for (int j = 0; j < 8; ++j)
                    d[j] = pkbf(dwv[2 * j] * s, dwv[2 * j + 1] * s);
            } else {
                #pragma unroll
                for (int j = 0; j < 16; ++j)
                    vh[(c0 + j) * STR_V + lane] = sbf(dwv[j]);
            }
        }

        // ======== attention per head ========
        for (int h2 = 0; h2 < 2; ++h2) {
            const int h = it * 2 + h2, ch0 = h2 * 32;
            __syncthreads();     // q/k/v ready; lbuf (prev P) consumed
            // ---- S = q @ k^T ; key tile = wid ----
            {
                f32x4 S[4];
                #pragma unroll
                for (int mt = 0; mt < 4; ++mt) S[mt] = f32x4{0.f, 0.f, 0.f, 0.f};
                bf16x8 bk = *(const bf16x8*)&kh[(wid * 16 + l15) * STR_QK + ch0 + quad * 8];
                #pragma unroll
                for (int mt = 0; mt < 4; ++mt) {
                    bf16x8 aq = *(const bf16x8*)&qh[(mt * 16 + l15) * STR_QK + ch0 + quad * 8];
                    S[mt] = __builtin_amdgcn_mfma_f32_16x16x32_bf16(aq, bk, S[mt], 0, 0, 0);
                }
                const int col = wid * 16 + l15, ky = col >> 3, kx = col & 7;
                #pragma unroll
                for (int mt = 0; mt < 4; ++mt)
                    #pragma unroll
                    for (int r = 0; r < 4; ++r) {
                        int row = mt * 16 + quad * 4 + r;
                        int qy = row >> 3, qx = row & 7;
                        int ridx = (qy - ky + 7) * 15 + (qx - kx + 7);
                        lbuf[row * STR_LB + col] = S[mt][r] + btab[ridx * 6 + h] + gmask[row * 64 + col];
                    }
            }
            __syncthreads();
            // ---- softmax (4 threads per row) + P (bf16, in-place over lbuf) ----
            {
                int srow = tid >> 2, sub = tid & 3;
                float t[16];
                const f32x4* sr = (const f32x4*)&lbuf[srow * STR_LB + sub * 16];
                *(f32x4*)&t[0] = sr[0]; *(f32x4*)&t[4] = sr[1];
                *(f32x4*)&t[8] = sr[2]; *(f32x4*)&t[12] = sr[3];
                float mx = t[0];
                #pragma unroll
                for (int j = 1; j < 16; ++j) mx = fmaxf(mx, t[j]);
                mx = fmaxf(mx, __shfl_xor(mx, 1, 64));
                mx = fmaxf(mx, __shfl_xor(mx, 2, 64));
                float s = 0.f;
                #pragma unroll
                for (int j = 0; j < 16; ++j) { t[j] = __expf(t[j] - mx); s += t[j]; }
                s += __shfl_xor(s, 1, 64);
                s += __shfl_xor(s, 2, 64);
                float inv = 1.f / s;
                __syncthreads();     // all S reads done before bf16 overwrite
                u32* pw = (u32*)(((u16*)lbuf) + srow * (STR_LB * 2) + sub * 16);
                #pragma unroll
                for (int j = 0; j < 8; ++j)
                    pw[j] = pkbf(t[2 * j] * inv, t[2 * j + 1] * inv);
            }
            __syncthreads();
            // ---- O = P @ v ; query tile = wid, 2 ch tiles ----
            {
                f32x4 O[2];
                O[0] = f32x4{0.f, 0.f, 0.f, 0.f};
                O[1] = f32x4{0.f, 0.f, 0.f, 0.f};
                #pragma unroll
                for (int kf = 0; kf < 2; ++kf) {
                    bf16x8 ap = *(const bf16x8*)(((const u16*)lbuf) + (wid * 16 + l15) * (STR_LB * 2) + kf * 32 + quad * 8);
                    #pragma unroll
                    for (int nt = 0; nt < 2; ++nt) {
                        bf16x8 bv = *(const bf16x8*)&vh[(ch0 + nt * 16 + l15) * STR_V + kf * 32 + quad * 8];
                        O[nt] = __builtin_amdgcn_mfma_f32_16x16x32_bf16(ap, bv, O[nt], 0, 0, 0);
                    }
                }
                #pragma unroll
                for (int nt = 0; nt < 2; ++nt)
                    #pragma unroll
                    for (int r = 0; r < 4; ++r)
                        oh[(wid * 16 + quad * 4 + r) * STR_OH + ch0 + nt * 16 + l15] = sbf(O[nt][r]);
            }
        }

        __syncthreads();   // oh complete
        // ======== proj partial: acc += O(64 ch) @ projW ========
        {
            #pragma unroll
            for (int kf = 0; kf < 2; ++kf) {
                bf16x8 A4[4];
                #pragma unroll
                for (int mt = 0; mt < 4; ++mt)
                    A4[mt] = *(const bf16x8*)&oh[(mt * 16 + l15) * STR_OH + kf * 32 + quad * 8];
                #pragma unroll
                for (int nt = 0; nt < 3; ++nt) {
                    const float* wp = proj_w + (size_t)(wid * 48 + nt * 16 + l15) * 192 + it * 64 + kf * 32 + quad * 8;
                    float4 b0 = *(const float4*)wp, b1 = *(const float4*)(wp + 4);
                    union { u32 u[4]; bf16x8 v; } fb;
                    fb.u[0] = pkbf(b0.x, b0.y); fb.u[1] = pkbf(b0.z, b0.w);
                    fb.u[2] = pkbf(b1.x, b1.y); fb.u[3] = pkbf(b1.z, b1.w);
                    #pragma unroll
                    for (int mt = 0; mt < 4; ++mt)
                        accP[nt * 4 + mt] = __builtin_amdgcn_mfma_f32_16x16x32_bf16(A4[mt], fb.v, accP[nt * 4 + mt], 0, 0, 0);
                }
            }
        }
    }

    // ======== epilogue: transpose via lbuf, coalesced NCHW store ========
    __syncthreads();
    {
        float* ob = out + (size_t)b * 12288;
        for (int rr = 0; rr < 3; ++rr) {
            float pb = proj_b[wid * 48 + rr * 16 + l15];
            #pragma unroll
            for (int mt = 0; mt < 4; ++mt)
                #pragma unroll
                for (int r = 0; r < 4; ++r)
                    lbuf[(wid * 16 + l15) * STR_LB + mt * 16 + quad * 4 + r] = accP[rr * 4 + mt][r] + pb;
            __syncthreads();
            {
                int ol = tid >> 2, sub = tid & 3;
                int ocg = (ol >> 4) * 48 + rr * 16 + (ol & 15);
                const float4* srp = (const float4*)&lbuf[ol * STR_LB + sub * 16];
                float4* dst = (float4*)(ob + (size_t)ocg * 64 + sub * 16);
                dst[0] = srp[0]; dst[1] = srp[1]; dst[2] = srp[2]; dst[3] = srp[3];
            }
            __syncthreads();
        }
    }
}

extern "C" void kernel_launch(void* const* d_in, const int* in_sizes, int n_in,
                              void* d_out, int out_size, void* d_ws, size_t ws_size,
                              hipStream_t stream)
{
    const float* x      = (const float*)d_in[0];
    const float* mask   = (const float*)d_in[1];
    const float* qkv_w  = (const float*)d_in[2];
    const float* qkv_b  = (const float*)d_in[3];
    const float* dw_w   = (const float*)d_in[4];
    const float* dw_b   = (const float*)d_in[5];
    const float* proj_w = (const float*)d_in[6];
    const float* proj_b = (const float*)d_in[7];
    const float* temp   = (const float*)d_in[8];
    const float* btab   = (const float*)d_in[9];
    float* out = (float*)d_out;

    const int b  = in_sizes[0] / 12288;          // 2048
    const int nW = in_sizes[1] / 4096;           // 512

    wattn_mfma<<<dim3(b), dim3(256), 0, stream>>>(
        x, mask, qkv_w, qkv_b, dw_w, dw_b, proj_w, proj_b, temp, btab, out, nW);
}

// Round 3
// 418.887 us; speedup vs baseline: 6.4478x; 1.1522x over previous
//
#include <hip/hip_runtime.h>

typedef unsigned short u16;
typedef unsigned int   u32;
typedef __attribute__((ext_vector_type(8))) short bf16x8;
typedef __attribute__((ext_vector_type(4))) float f32x4;

#define STR_XS 200   // u16/row: 400 B (16B-mult, bank stride 4 -> 2-way free)
#define STR_LB 68    // f32/row: 272 B
#define STR_Q  72    // u16/row: 144 B (16B-mult)

// Persistent preprocessed constants (rewritten every launch by prep kernel)
__device__ u16   g_wq[576 * 192];   // qkv_w bf16 [o][ci]
__device__ u16   g_wp[192 * 192];   // proj_w bf16 [o][ci]
__device__ float g_bh[6 * 64 * 64]; // rel bias expanded [h][m][n]
__device__ float g_dwt[10 * 576];   // dw weights [tap 0..8][o], tap 9 = dw_b

// round-half-up bf16 (vs RNE: differs only at exact ties, 1 ulp)
__device__ __forceinline__ u32 pkbf(float lo, float hi) {
    return __builtin_amdgcn_perm(__float_as_uint(hi) + 0x8000u,
                                 __float_as_uint(lo) + 0x8000u, 0x07060302u);
}
__device__ __forceinline__ u16 sbf(float f) {
    return (u16)((__float_as_uint(f) + 0x8000u) >> 16);
}

__global__ __launch_bounds__(256) void prep(
    const float* __restrict__ qkv_w, const float* __restrict__ proj_w,
    const float* __restrict__ btab, const float* __restrict__ dw_w,
    const float* __restrict__ dw_b)
{
    int i = blockIdx.x * 256 + threadIdx.x;
    if (i < 110592) { g_wq[i] = sbf(qkv_w[i]); return; }
    i -= 110592;
    if (i < 36864) { g_wp[i] = sbf(proj_w[i]); return; }
    i -= 36864;
    if (i < 24576) {
        int h = i >> 12, m = (i >> 6) & 63, n = i & 63;
        int ry = (m >> 3) - (n >> 3) + 7, rx = (m & 7) - (n & 7) + 7;
        g_bh[i] = btab[(ry * 15 + rx) * 6 + h];
        return;
    }
    i -= 24576;
    if (i < 5760) {
        int tap = i / 576, o = i - tap * 576;
        g_dwt[i] = (tap < 9) ? dw_w[o * 9 + tap] : dw_b[o];
    }
}

// One block per window. 256 threads = 4 waves. LDS 79,872 B -> 2 blocks/CU.
__global__ __launch_bounds__(256, 2) void wattn(
    const float* __restrict__ x, const float* __restrict__ mask,
    const float* __restrict__ qkv_b, const float* __restrict__ temp,
    const float* __restrict__ proj_b, float* __restrict__ out, int nW)
{
    const int b    = blockIdx.x;
    const int tid  = threadIdx.x;
    const int lane = tid & 63;
    const int wid  = __builtin_amdgcn_readfirstlane(tid >> 6);
    const int quad = lane >> 4, l15 = lane & 15;

    __shared__ u16   xs[64 * STR_XS];   // 25600 B  x bf16 [pix][ch]
    __shared__ float arena[64 * STR_LB];// 17408 B  conv1 fp32 / wave-private P / epilogue
    __shared__ u16   qh[64 * STR_Q];    //  9216 B  [pix][ch64]
    __shared__ u16   kh[64 * STR_Q];
    __shared__ u16   vh[64 * STR_Q];    //           [ch64][pix]
    __shared__ u16   oh[64 * STR_Q];    //           [pix][ch64]

    // ---- stage x -> xs (bf16) ----
    {
        const float* xb = x + (size_t)b * 12288;
        #pragma unroll
        for (int r = 0; r < 12; ++r) {
            int i4 = tid + r * 256;
            int pp = i4 / 48, c0 = (i4 % 48) * 4;
            float4 v = *(const float4*)(xb + pp * 192 + c0);
            u32* d = (u32*)&xs[pp * STR_XS + c0];
            d[0] = pkbf(v.x, v.y);
            d[1] = pkbf(v.z, v.w);
        }
    }

    const float* gmask = mask + (size_t)(b % nW) * 4096;
    const int p  = wid * 16 + l15;          // pixel owned in dw phase
    const int py = p >> 3, px = p & 7;

    f32x4 accP[12];
    #pragma unroll
    for (int i = 0; i < 12; ++i) accP[i] = f32x4{0.f, 0.f, 0.f, 0.f};

    for (int it = 0; it < 3; ++it) {
        // ======== q,k,v chunks (64 ch = head pair it*2, it*2+1) ========
        for (int g = 0; g < 3; ++g) {
            const int obase = g * 192 + it * 64;
            __syncthreads();   // arena write-safe (prev readers done)
            // ---- conv1 1x1 chunk: N-split, col tile = wid ----
            {
                f32x4 C[4];
                #pragma unroll
                for (int mt = 0; mt < 4; ++mt) C[mt] = f32x4{0.f, 0.f, 0.f, 0.f};
                const u16* wb = g_wq + (size_t)(obase + wid * 16 + l15) * 192;
                #pragma unroll
                for (int kf = 0; kf < 6; ++kf) {
                    bf16x8 bw = *(const bf16x8*)(wb + kf * 32 + quad * 8);
                    #pragma unroll
                    for (int mt = 0; mt < 4; ++mt) {
                        bf16x8 a = *(const bf16x8*)&xs[(mt * 16 + l15) * STR_XS + kf * 32 + quad * 8];
                        C[mt] = __builtin_amdgcn_mfma_f32_16x16x32_bf16(a, bw, C[mt], 0, 0, 0);
                    }
                }
                float qb = qkv_b[obase + wid * 16 + l15];
                #pragma unroll
                for (int mt = 0; mt < 4; ++mt)
                    #pragma unroll
                    for (int r = 0; r < 4; ++r)
                        arena[(mt * 16 + quad * 4 + r) * STR_LB + wid * 16 + l15] = C[mt][r] + qb;
            }
            __syncthreads();   // conv1 out ready
            // ---- depthwise 3x3: pixel = p, ch = quad*16.. ----
            const int c0 = quad * 16;
            const float* dwt = g_dwt + obase + c0;
            float dwv[16];
            {
                const float* bs = dwt + 9 * 576;
                *(f32x4*)&dwv[0]  = *(const f32x4*)(bs);
                *(f32x4*)&dwv[4]  = *(const f32x4*)(bs + 4);
                *(f32x4*)&dwv[8]  = *(const f32x4*)(bs + 8);
                *(f32x4*)&dwv[12] = *(const f32x4*)(bs + 12);
            }
            #pragma unroll
            for (int dy = -1; dy <= 1; ++dy) {
                int yy = py + dy;
                if ((unsigned)yy < 8u) {
                    #pragma unroll
                    for (int dx = -1; dx <= 1; ++dx) {
                        int xx = px + dx;
                        if ((unsigned)xx < 8u) {
                            const float* src = &arena[(yy * 8 + xx) * STR_LB + c0];
                            const float* wt  = dwt + ((dy + 1) * 3 + dx + 1) * 576;
                            float nb[16], wv[16];
                            *(f32x4*)&nb[0]  = *(const f32x4*)(src);
                            *(f32x4*)&nb[4]  = *(const f32x4*)(src + 4);
                            *(f32x4*)&nb[8]  = *(const f32x4*)(src + 8);
                            *(f32x4*)&nb[12] = *(const f32x4*)(src + 12);
                            *(f32x4*)&wv[0]  = *(const f32x4*)(wt);
                            *(f32x4*)&wv[4]  = *(const f32x4*)(wt + 4);
                            *(f32x4*)&wv[8]  = *(const f32x4*)(wt + 8);
                            *(f32x4*)&wv[12] = *(const f32x4*)(wt + 12);
                            #pragma unroll
                            for (int j = 0; j < 16; ++j)
                                dwv[j] = fmaf(nb[j], wv[j], dwv[j]);
                        }
                    }
                }
            }
            if (g < 2) {
                // in-wave L2 norm over the head's 32 ch (quad-pair exchange)
                float ss = 0.f;
                #pragma unroll
                for (int j = 0; j < 16; ++j) ss = fmaf(dwv[j], dwv[j], ss);
                ss += __shfl_xor(ss, 16, 64);
                float tf = (g == 0) ? temp[it * 2 + (quad >> 1)] : 1.f;
                float s = tf / fmaxf(sqrtf(ss), 1e-12f);
                u16* dst = (g == 0) ? qh : kh;
                u32* d = (u32*)&dst[p * STR_Q + c0];
                #pragma unroll
                for (int j = 0; j < 8; ++j)
                    d[j] = pkbf(dwv[2 * j] * s, dwv[2 * j + 1] * s);
            } else {
                #pragma unroll
                for (int j = 0; j < 16; ++j)
                    vh[(c0 + j) * STR_Q + p] = sbf(dwv[j]);
            }
        }
        __syncthreads();   // q,k,v ready; arena free for P scratch

        // ======== attention: wave owns q-rows wid*16.., no barriers ========
        u16* Pw = ((u16*)arena) + wid * (16 * STR_Q);   // wave-private P
        for (int h2 = 0; h2 < 2; ++h2) {
            const int h = it * 2 + h2, ch0 = h2 * 32;
            f32x4 S[4];
            #pragma unroll
            for (int nt = 0; nt < 4; ++nt) S[nt] = f32x4{0.f, 0.f, 0.f, 0.f};
            bf16x8 aq = *(const bf16x8*)&qh[(wid * 16 + l15) * STR_Q + ch0 + quad * 8];
            #pragma unroll
            for (int nt = 0; nt < 4; ++nt) {
                bf16x8 bk = *(const bf16x8*)&kh[(nt * 16 + l15) * STR_Q + ch0 + quad * 8];
                S[nt] = __builtin_amdgcn_mfma_f32_16x16x32_bf16(aq, bk, S[nt], 0, 0, 0);
            }
            const float* bh = g_bh + h * 4096 + (wid * 16 + quad * 4) * 64 + l15;
            const float* gm = gmask + (wid * 16 + quad * 4) * 64 + l15;
            #pragma unroll
            for (int nt = 0; nt < 4; ++nt)
                #pragma unroll
                for (int r = 0; r < 4; ++r)
                    S[nt][r] += bh[r * 64 + nt * 16] + gm[r * 64 + nt * 16];
            // in-register softmax per row (reduce over l15)
            #pragma unroll
            for (int r = 0; r < 4; ++r) {
                float mx = fmaxf(fmaxf(S[0][r], S[1][r]), fmaxf(S[2][r], S[3][r]));
                mx = fmaxf(mx, __shfl_xor(mx, 1, 64));
                mx = fmaxf(mx, __shfl_xor(mx, 2, 64));
                mx = fmaxf(mx, __shfl_xor(mx, 4, 64));
                mx = fmaxf(mx, __shfl_xor(mx, 8, 64));
                float e0 = __expf(S[0][r] - mx), e1 = __expf(S[1][r] - mx);
                float e2 = __expf(S[2][r] - mx), e3 = __expf(S[3][r] - mx);
                float sm = (e0 + e1) + (e2 + e3);
                sm += __shfl_xor(sm, 1, 64);
                sm += __shfl_xor(sm, 2, 64);
                sm += __shfl_xor(sm, 4, 64);
                sm += __shfl_xor(sm, 8, 64);
                float iv = 1.f / sm;
                u16* pr = Pw + (quad * 4 + r) * STR_Q + l15;
                pr[0]  = sbf(e0 * iv);
                pr[16] = sbf(e1 * iv);
                pr[32] = sbf(e2 * iv);
                pr[48] = sbf(e3 * iv);
            }
            // PV (P read back wave-synchronously)
            f32x4 O[2];
            O[0] = f32x4{0.f, 0.f, 0.f, 0.f};
            O[1] = f32x4{0.f, 0.f, 0.f, 0.f};
            #pragma unroll
            for (int kf = 0; kf < 2; ++kf) {
                bf16x8 ap = *(const bf16x8*)(Pw + l15 * STR_Q + kf * 32 + quad * 8);
                #pragma unroll
                for (int nt = 0; nt < 2; ++nt) {
                    bf16x8 bv = *(const bf16x8*)&vh[(ch0 + nt * 16 + l15) * STR_Q + kf * 32 + quad * 8];
                    O[nt] = __builtin_amdgcn_mfma_f32_16x16x32_bf16(ap, bv, O[nt], 0, 0, 0);
                }
            }
            #pragma unroll
            for (int nt = 0; nt < 2; ++nt)
                #pragma unroll
                for (int r = 0; r < 4; ++r)
                    oh[(wid * 16 + quad * 4 + r) * STR_Q + ch0 + nt * 16 + l15] = sbf(O[nt][r]);
        }
        __syncthreads();   // oh ready (also: all P reads done before next arena use)

        // ======== proj partial: acc += O(64 ch) @ Wp ========
        #pragma unroll
        for (int kf = 0; kf < 2; ++kf) {
            bf16x8 A4[4];
            #pragma unroll
            for (int mt = 0; mt < 4; ++mt)
                A4[mt] = *(const bf16x8*)&oh[(mt * 16 + l15) * STR_Q + kf * 32 + quad * 8];
            #pragma unroll
            for (int nt = 0; nt < 3; ++nt) {
                bf16x8 bw = *(const bf16x8*)(g_wp + (size_t)(wid * 48 + nt * 16 + l15) * 192 + it * 64 + kf * 32 + quad * 8);
                #pragma unroll
                for (int mt = 0; mt < 4; ++mt)
                    accP[nt * 4 + mt] = __builtin_amdgcn_mfma_f32_16x16x32_bf16(A4[mt], bw, accP[nt * 4 + mt], 0, 0, 0);
            }
        }
    }

    // ======== epilogue: transpose via arena, coalesced NCHW store ========
    __syncthreads();
    {
        float* ob = out + (size_t)b * 12288;
        for (int rr = 0; rr < 3; ++rr) {
            float pb = proj_b[wid * 48 + rr * 16 + l15];
            #pragma unroll
            for (int mt = 0; mt < 4; ++mt)
                #pragma unroll
                for (int r = 0; r < 4; ++r)
                    arena[(wid * 16 + l15) * STR_LB + mt * 16 + quad * 4 + r] = accP[rr * 4 + mt][r] + pb;
            __syncthreads();
            {
                int ol = tid >> 2, sub = tid & 3;
                int ocg = (ol >> 4) * 48 + rr * 16 + (ol & 15);
                const float4* srp = (const float4*)&arena[ol * STR_LB + sub * 16];
                float4* dst = (float4*)(ob + (size_t)ocg * 64 + sub * 16);
                dst[0] = srp[0]; dst[1] = srp[1]; dst[2] = srp[2]; dst[3] = srp[3];
            }
            __syncthreads();
        }
    }
}

extern "C" void kernel_launch(void* const* d_in, const int* in_sizes, int n_in,
                              void* d_out, int out_size, void* d_ws, size_t ws_size,
                              hipStream_t stream)
{
    const float* x      = (const float*)d_in[0];
    const float* mask   = (const float*)d_in[1];
    const float* qkv_w  = (const float*)d_in[2];
    const float* qkv_b  = (const float*)d_in[3];
    const float* dw_w   = (const float*)d_in[4];
    const float* dw_b   = (const float*)d_in[5];
    const float* proj_w = (const float*)d_in[6];
    const float* proj_b = (const float*)d_in[7];
    const float* temp   = (const float*)d_in[8];
    const float* btab   = (const float*)d_in[9];
    float* out = (float*)d_out;

    const int b  = in_sizes[0] / 12288;   // 2048
    const int nW = in_sizes[1] / 4096;    // 512

    prep<<<dim3(695), dim3(256), 0, stream>>>(qkv_w, proj_w, btab, dw_w, dw_b);
    wattn<<<dim3(b), dim3(256), 0, stream>>>(x, mask, qkv_b, temp, proj_b, out, nW);
}